// Round 1
// 511.947 us; speedup vs baseline: 1.0927x; 1.0927x over previous
//
#include <hip/hip_runtime.h>
#include <math.h>

typedef __attribute__((ext_vector_type(8))) short short8;
typedef __attribute__((ext_vector_type(4))) float floatx4;
typedef __attribute__((ext_vector_type(4))) unsigned int uintx4;
typedef __attribute__((ext_vector_type(2))) unsigned int uintx2;

#define MFMA16(a, b, c) __builtin_amdgcn_mfma_f32_16x16x32_bf16((a), (b), (c), 0, 0, 0)

// log2(e) * (1/sqrt(64)) — folded into Q so attention works in exp2 domain
#define QSCALE 0.18033688011112042f

__device__ __forceinline__ unsigned short f2bf(float x) {
    unsigned int u = __float_as_uint(x);
    u += 0x7fffu + ((u >> 16) & 1u);   // round-to-nearest-even
    return (unsigned short)(u >> 16);
}

__device__ __forceinline__ short8 lds8(const unsigned short* p) {
    return *reinterpret_cast<const short8*>(p);
}

// async global->LDS, 16B per lane; LDS dest = wave-uniform base + lane*16
__device__ __forceinline__ void g2l16(const unsigned short* g, unsigned short* l) {
    __builtin_amdgcn_global_load_lds(
        (const __attribute__((address_space(1))) unsigned int*)g,
        (__attribute__((address_space(3))) unsigned int*)l,
        16, 0, 0);
}

// pack two f32 -> bf16x2 dword (RNE): low = a, high = b
__device__ __forceinline__ unsigned int cvtpk(float a, float b) {
    unsigned int r;
    asm("v_cvt_pk_bf16_f32 %0, %1, %2" : "=v"(r) : "v"(a), "v"(b));
    return r;
}

// swap lanes[32:63] of a with lanes[0:31] of b (both modified)
__device__ __forceinline__ void pl32swap(unsigned int& a, unsigned int& b) {
    asm("v_permlane32_swap_b32 %0, %1" : "+v"(a), "+v"(b));
}

// swap odd 16-lane groups of a with even 16-lane groups of b (both modified)
__device__ __forceinline__ void pl16swap(unsigned int& a, unsigned int& b) {
    asm("v_permlane16_swap_b32 %0, %1" : "+v"(a), "+v"(b));
}

// ---------------- prep: fp32 -> bf16 convert (vectorized) ----------------
__global__ void cvt_bf16(const float* __restrict__ src, unsigned short* __restrict__ dst, int n4) {
    int i = blockIdx.x * blockDim.x + threadIdx.x;
    if (i >= n4) return;
    float4 v = reinterpret_cast<const float4*>(src)[i];
    ushort4 o;
    o.x = f2bf(v.x); o.y = f2bf(v.y); o.z = f2bf(v.z); o.w = f2bf(v.w);
    reinterpret_cast<ushort4*>(dst)[i] = o;
}

// ---------------- prep: K window convert (coalesced both sides) ----------------
__global__ void prep_k(const float* __restrict__ kc, unsigned short* __restrict__ Kw) {
    int i = blockIdx.x * blockDim.x + threadIdx.x;   // 0 .. 262143
    int d4  = (i & 15) * 4;
    int s   = (i >> 4) & 1023;
    int bkv = i >> 14;
    size_t src = ((size_t)bkv * 4096 + 3072 + s) * 64 + d4;
    float4 kv = *reinterpret_cast<const float4*>(kc + src);
    ushort4 ko;
    ko.x = f2bf(kv.x); ko.y = f2bf(kv.y); ko.z = f2bf(kv.z); ko.w = f2bf(kv.w);
    *reinterpret_cast<ushort4*>(Kw + ((size_t)bkv * 1024 + s) * 64 + d4) = ko;
}

// ---------------- prep: V window transpose via LDS tile ----------------
__global__ void prep_v(const float* __restrict__ vc, unsigned short* __restrict__ Vt) {
    __shared__ unsigned short tl[64][72];
    const int bkv = blockIdx.x >> 4;
    const int s0  = (blockIdx.x & 15) * 64;
    const int t   = threadIdx.x;
    const int sl  = t >> 2;
    const int dq  = (t & 3) * 16;
    const float* src = vc + ((size_t)bkv * 4096 + 3072 + s0 + sl) * 64 + dq;
    float4 v0 = reinterpret_cast<const float4*>(src)[0];
    float4 v1 = reinterpret_cast<const float4*>(src)[1];
    float4 v2 = reinterpret_cast<const float4*>(src)[2];
    float4 v3 = reinterpret_cast<const float4*>(src)[3];
    tl[dq +  0][sl] = f2bf(v0.x); tl[dq +  1][sl] = f2bf(v0.y);
    tl[dq +  2][sl] = f2bf(v0.z); tl[dq +  3][sl] = f2bf(v0.w);
    tl[dq +  4][sl] = f2bf(v1.x); tl[dq +  5][sl] = f2bf(v1.y);
    tl[dq +  6][sl] = f2bf(v1.z); tl[dq +  7][sl] = f2bf(v1.w);
    tl[dq +  8][sl] = f2bf(v2.x); tl[dq +  9][sl] = f2bf(v2.y);
    tl[dq + 10][sl] = f2bf(v2.z); tl[dq + 11][sl] = f2bf(v2.w);
    tl[dq + 12][sl] = f2bf(v3.x); tl[dq + 13][sl] = f2bf(v3.y);
    tl[dq + 14][sl] = f2bf(v3.z); tl[dq + 15][sl] = f2bf(v3.w);
    __syncthreads();
    const int dl = t >> 2;
    const int sc = (t & 3) * 16;
    unsigned short* dst = Vt + ((size_t)bkv * 64 + dl) * 1024 + s0 + sc;
    short8 x0 = *reinterpret_cast<const short8*>(&tl[dl][sc]);
    short8 x1 = *reinterpret_cast<const short8*>(&tl[dl][sc + 8]);
    *reinterpret_cast<short8*>(dst)     = x0;
    *reinterpret_cast<short8*>(dst + 8) = x1;
}

// ---------------- bf16 MFMA GEMM (m97 structure): C = A[M,K] * Bt[N,K]^T ----------------
template <int EPI>
__global__ __launch_bounds__(256)
void gemm_bt(const unsigned short* __restrict__ A,
             const unsigned short* __restrict__ Bt,
             float* __restrict__ Cf,
             unsigned short* __restrict__ Cb) {
    constexpr int K = 2048;
    __shared__ unsigned short As[128 * 32];
    __shared__ unsigned short Bs[128 * 32];

    const int tid  = threadIdx.x;
    const int lane = tid & 63;
    const int l15  = lane & 15;
    const int quad = lane >> 4;
    const int wid  = tid >> 6;
    const int wm   = (wid & 1) * 64;
    const int wn   = (wid >> 1) * 64;

    const int bn = blockIdx.x & 15;
    const int bm = blockIdx.x >> 4;

    const int row0 = tid >> 2;
    const int kc8  = (tid & 3) * 8;
    const unsigned short* Ag0 = A  + (size_t)(bm * 128 + row0) * K + kc8;
    const unsigned short* Ag1 = Ag0 + (size_t)64 * K;
    const unsigned short* Bg0 = Bt + (size_t)(bn * 128 + row0) * K + kc8;
    const unsigned short* Bg1 = Bg0 + (size_t)64 * K;
    unsigned short* AsW0 = As + wid * 512;
    unsigned short* AsW1 = As + 2048 + wid * 512;
    unsigned short* BsW0 = Bs + wid * 512;
    unsigned short* BsW1 = Bs + 2048 + wid * 512;

    floatx4 c00 = {0,0,0,0}, c01 = {0,0,0,0}, c02 = {0,0,0,0}, c03 = {0,0,0,0};
    floatx4 c10 = {0,0,0,0}, c11 = {0,0,0,0}, c12 = {0,0,0,0}, c13 = {0,0,0,0};
    floatx4 c20 = {0,0,0,0}, c21 = {0,0,0,0}, c22 = {0,0,0,0}, c23 = {0,0,0,0};
    floatx4 c30 = {0,0,0,0}, c31 = {0,0,0,0}, c32 = {0,0,0,0}, c33 = {0,0,0,0};

    for (int k0 = 0; k0 < K; k0 += 32) {
        __syncthreads();
        g2l16(Ag0 + k0, AsW0);
        g2l16(Ag1 + k0, AsW1);
        g2l16(Bg0 + k0, BsW0);
        g2l16(Bg1 + k0, BsW1);
        __syncthreads();

        short8 a0 = lds8(&As[(wm +  0 + l15) * 32 + quad * 8]);
        short8 a1 = lds8(&As[(wm + 16 + l15) * 32 + quad * 8]);
        short8 a2 = lds8(&As[(wm + 32 + l15) * 32 + quad * 8]);
        short8 a3 = lds8(&As[(wm + 48 + l15) * 32 + quad * 8]);
        short8 b0 = lds8(&Bs[(wn +  0 + l15) * 32 + quad * 8]);
        short8 b1 = lds8(&Bs[(wn + 16 + l15) * 32 + quad * 8]);
        short8 b2 = lds8(&Bs[(wn + 32 + l15) * 32 + quad * 8]);
        short8 b3 = lds8(&Bs[(wn + 48 + l15) * 32 + quad * 8]);

        c00 = MFMA16(a0, b0, c00); c01 = MFMA16(a0, b1, c01);
        c02 = MFMA16(a0, b2, c02); c03 = MFMA16(a0, b3, c03);
        c10 = MFMA16(a1, b0, c10); c11 = MFMA16(a1, b1, c11);
        c12 = MFMA16(a1, b2, c12); c13 = MFMA16(a1, b3, c13);
        c20 = MFMA16(a2, b0, c20); c21 = MFMA16(a2, b1, c21);
        c22 = MFMA16(a2, b2, c22); c23 = MFMA16(a2, b3, c23);
        c30 = MFMA16(a3, b0, c30); c31 = MFMA16(a3, b1, c31);
        c32 = MFMA16(a3, b2, c32); c33 = MFMA16(a3, b3, c33);
    }

#define EPI_TILE(i, j, C) do {                                                  \
    _Pragma("unroll")                                                           \
    for (int r = 0; r < 4; ++r) {                                               \
        int row = bm * 128 + wm + (i) * 16 + quad * 4 + r;                      \
        int col = bn * 128 + wn + (j) * 16 + l15;                               \
        float v = (C)[r];                                                       \
        if (EPI == 0) {                                                         \
            float p = __shfl_xor(v, 1);                                         \
            int t = row & 4095, b = row >> 12;                                  \
            int hh = col >> 6, d = col & 63;                                    \
            float f = (float)t * exp2f(-(float)(d >> 1) * 0.41524101186092f);   \
            float sn, cs; __sincosf(f, &sn, &cs);                               \
            float o = (d & 1) ? (p * sn + v * cs) : (v * cs - p * sn);          \
            o *= QSCALE;                                                        \
            float po = __shfl_xor(o, 1);                                        \
            if (!(lane & 1)) {                                                  \
                unsigned int pk = (unsigned int)f2bf(o) |                       \
                                  ((unsigned int)f2bf(po) << 16);               \
                *reinterpret_cast<unsigned int*>(                               \
                    Cb + ((size_t)((b * 32 + hh) * 4096 + t)) * 64 + d) = pk;   \
            }                                                                   \
        } else {                                                                \
            Cf[(size_t)row * 2048 + col] = v;                                   \
        }                                                                       \
    }                                                                           \
} while (0)

    EPI_TILE(0, 0, c00); EPI_TILE(0, 1, c01); EPI_TILE(0, 2, c02); EPI_TILE(0, 3, c03);
    EPI_TILE(1, 0, c10); EPI_TILE(1, 1, c11); EPI_TILE(1, 2, c12); EPI_TILE(1, 3, c13);
    EPI_TILE(2, 0, c20); EPI_TILE(2, 1, c21); EPI_TILE(2, 2, c22); EPI_TILE(2, 3, c23);
    EPI_TILE(3, 0, c30); EPI_TILE(3, 1, c31); EPI_TILE(3, 2, c32); EPI_TILE(3, 3, c33);
#undef EPI_TILE
}

// ---------------- flash attention over 1024-key window ----------------
// Swapped-operand form (T12): QK^T computed as S^T = mfma(K_frag, Q_frag) so
// each lane holds P[query = l15][its 16 keys] in registers. P -> bf16 B-frag
// for PV is built fully in-register: 8 v_cvt_pk_bf16_f32 + 4 v_permlane32_swap
// + 4 v_permlane16_swap per tile (no LDS P buffer, no ds_swizzle storm).
// PV computed as O^T = mfma(V^T_frag, P^T_frag) using the SAME V fragments
// (A-frag of V^T == B-frag of V). LDS = 32 KiB -> 5 blocks/CU.
//
// Permutation algebra (verified): source X[c][d] at lane (b5,b4) holds keys
// 16c + 8*b5 + 4*b4 + 2d, 2d+1. Target frag dword j=2*j1+j0 at quad (h,q)
// needs keys 16h + 8q + 4*j1 + 2*j0. pl32swap(X[0][d], X[1][d]) then
// pl16swap of the results yields Y[j1=0][j0=d] and Y[j1=1][j0=d].
__global__ __launch_bounds__(256, 5)
void attn(const unsigned short* __restrict__ Q,
          const unsigned short* __restrict__ Kw,
          const unsigned short* __restrict__ Vt,
          unsigned short* __restrict__ O) {
    const int blk   = blockIdx.x;
    const int qtile = blk & 63;
    const int bh    = blk >> 6;
    const int h     = bh & 31;
    const int b     = bh >> 5;
    const int kvh   = h >> 2;

    const int tid  = threadIdx.x;
    const int lane = tid & 63;
    const int l15  = lane & 15;
    const int quad = lane >> 4;
    const int wid  = tid >> 6;
    const int qt0  = qtile * 64 + wid * 16;

    const unsigned short* Qp = Q  + ((size_t)bh * 4096 + qt0) * 64;
    const unsigned short* Kp = Kw + (size_t)(b * 8 + kvh) * 1024 * 64;
    const unsigned short* Vp = Vt + (size_t)(b * 8 + kvh) * 64 * 1024;

    // [buf][frag(8) * 512 + lane*8]; frag (c*2+half) for K, (j*2+shalf) for V
    __shared__ unsigned short Ks[2][4096];
    __shared__ unsigned short Vs[2][4096];

    short8 qa0 = lds8(&Qp[l15 * 64 + quad * 8]);
    short8 qa1 = lds8(&Qp[l15 * 64 + 32 + quad * 8]);

    // staging source addrs: wave w stages K frag c=w (both halves), V frag j=w
    const unsigned short* gK = Kp + (size_t)(wid * 16 + l15) * 64 + quad * 8;
    const unsigned short* gV = Vp + (size_t)(wid * 16 + l15) * 1024 + quad * 8;

    const int ntiles = (qtile < 15 ? qtile + 1 : 16);       // block-uniform
    const int nkW    = (qt0 + 16 < 1024) ? qt0 + 16 : 1024; // per-wave keys
    const bool diag  = (qtile < 16);

    // prefetch tile 0
    g2l16(gK,      &Ks[0][wid * 1024]);
    g2l16(gK + 32, &Ks[0][wid * 1024 + 512]);
    g2l16(gV,      &Vs[0][wid * 1024]);
    g2l16(gV + 32, &Vs[0][wid * 1024 + 512]);

    floatx4 o0 = {0,0,0,0}, o1 = {0,0,0,0}, o2 = {0,0,0,0}, o3 = {0,0,0,0};
    float Lq = 0.f;
    float m = -INFINITY;

    for (int it = 0; it < ntiles; ++it) {
        __syncthreads();                         // staging of tile `it` complete
        const int cur = it & 1;
        if (it + 1 < ntiles) {                   // prefetch next into other buffer
            const int nxt = cur ^ 1;
            const unsigned short* gKn = gK + (it + 1) * 4096;
            const unsigned short* gVn = gV + (it + 1) * 64;
            g2l16(gKn,      &Ks[nxt][wid * 1024]);
            g2l16(gKn + 32, &Ks[nxt][wid * 1024 + 512]);
            g2l16(gVn,      &Vs[nxt][wid * 1024]);
            g2l16(gVn + 32, &Vs[nxt][wid * 1024 + 512]);
        }
        const int s0 = it << 6;
        const unsigned short* Kc = Ks[cur];
        const unsigned short* Vc = Vs[cur];

        // S^T = K·Q^T: lane holds S[key = s0 + c*16 + quad*4 + r][query = qt0 + l15]
        floatx4 sS[4];
#pragma unroll
        for (int c = 0; c < 4; ++c) {
            floatx4 z = {0, 0, 0, 0};
            z = MFMA16(lds8(Kc + c * 1024 + lane * 8), qa0, z);
            z = MFMA16(lds8(Kc + c * 1024 + 512 + lane * 8), qa1, z);
            sS[c] = z;
        }

        const bool last = (it == ntiles - 1);
        bool skipHi = false;
        if (last && diag) {                      // diagonal tile: causal mask
#pragma unroll
            for (int c = 0; c < 4; ++c)
#pragma unroll
                for (int r = 0; r < 4; ++r)
                    if (s0 + c * 16 + quad * 4 + r > qt0 + l15) sS[c][r] = -INFINITY;
            skipHi = (nkW - s0 <= 32);
        }

        // online softmax (exp2 domain), wave-uniform max
        float mx = sS[0][0];
#pragma unroll
        for (int c = 0; c < 4; ++c)
#pragma unroll
            for (int r = 0; r < 4; ++r) mx = fmaxf(mx, sS[c][r]);
#pragma unroll
        for (int off = 32; off >= 1; off >>= 1) mx = fmaxf(mx, __shfl_xor(mx, off));
        if (mx > m) {                            // wave-uniform rescale (rare after warmup)
            const float alpha = exp2f(m - mx);
            m = mx;
            o0 *= alpha; o1 *= alpha; o2 *= alpha; o3 *= alpha;
            Lq *= alpha;
        }
        float p[4][4];
#pragma unroll
        for (int c = 0; c < 4; ++c)
#pragma unroll
            for (int r = 0; r < 4; ++r) p[c][r] = exp2f(sS[c][r] - m);
        Lq += ((p[0][0] + p[0][1] + p[0][2] + p[0][3]) + (p[1][0] + p[1][1] + p[1][2] + p[1][3]))
            + ((p[2][0] + p[2][1] + p[2][2] + p[2][3]) + (p[3][0] + p[3][1] + p[3][2] + p[3][3]));

        // in-register P repack: keys 0-31 (chunks 0,1) -> pa_lo
        unsigned int a0 = cvtpk(p[0][0], p[0][1]);
        unsigned int a1 = cvtpk(p[0][2], p[0][3]);
        unsigned int a2 = cvtpk(p[1][0], p[1][1]);
        unsigned int a3 = cvtpk(p[1][2], p[1][3]);
        pl32swap(a0, a2); pl32swap(a1, a3);
        pl16swap(a0, a2); pl16swap(a1, a3);
        uintx4 tlo = {a0, a1, a2, a3};
        short8 pa_lo = __builtin_bit_cast(short8, tlo);

        // O^T += V^T · P^T : A-frag = V^T (same LDS frags), B-frag = pa
        o0 = MFMA16(lds8(Vc + 0 * 512 + lane * 8), pa_lo, o0);
        o1 = MFMA16(lds8(Vc + 2 * 512 + lane * 8), pa_lo, o1);
        o2 = MFMA16(lds8(Vc + 4 * 512 + lane * 8), pa_lo, o2);
        o3 = MFMA16(lds8(Vc + 6 * 512 + lane * 8), pa_lo, o3);
        if (!skipHi) {
            // keys 32-63 (chunks 2,3) -> pa_hi
            unsigned int b0 = cvtpk(p[2][0], p[2][1]);
            unsigned int b1 = cvtpk(p[2][2], p[2][3]);
            unsigned int b2 = cvtpk(p[3][0], p[3][1]);
            unsigned int b3 = cvtpk(p[3][2], p[3][3]);
            pl32swap(b0, b2); pl32swap(b1, b3);
            pl16swap(b0, b2); pl16swap(b1, b3);
            uintx4 thi = {b0, b1, b2, b3};
            short8 pa_hi = __builtin_bit_cast(short8, thi);
            o0 = MFMA16(lds8(Vc + 1 * 512 + lane * 8), pa_hi, o0);
            o1 = MFMA16(lds8(Vc + 3 * 512 + lane * 8), pa_hi, o1);
            o2 = MFMA16(lds8(Vc + 5 * 512 + lane * 8), pa_hi, o2);
            o3 = MFMA16(lds8(Vc + 7 * 512 + lane * 8), pa_hi, o3);
        }
    }

    // Lq holds this lane's keys only; total = sum across quads
    Lq += __shfl_xor(Lq, 16);
    Lq += __shfl_xor(Lq, 32);
    const float inv = 1.f / Lq;

    // O^T layout: lane holds O[q = qt0+l15][d = j*16 + quad*4 + r] -> 8B stores
    unsigned short* Op = O + (size_t)b * 4096 * 2048 + (size_t)(qt0 + l15) * 2048
                           + h * 64 + quad * 4;
    uintx2 w0, w1, w2, w3;
    w0.x = cvtpk(o0[0] * inv, o0[1] * inv); w0.y = cvtpk(o0[2] * inv, o0[3] * inv);
    w1.x = cvtpk(o1[0] * inv, o1[1] * inv); w1.y = cvtpk(o1[2] * inv, o1[3] * inv);
    w2.x = cvtpk(o2[0] * inv, o2[1] * inv); w2.y = cvtpk(o2[2] * inv, o2[3] * inv);
    w3.x = cvtpk(o3[0] * inv, o3[1] * inv); w3.y = cvtpk(o3[2] * inv, o3[3] * inv);
    *reinterpret_cast<uintx2*>(Op)      = w0;
    *reinterpret_cast<uintx2*>(Op + 16) = w1;
    *reinterpret_cast<uintx2*>(Op + 32) = w2;
    *reinterpret_cast<uintx2*>(Op + 48) = w3;
}

// ---------------- launch ----------------
extern "C" void kernel_launch(void* const* d_in, const int* in_sizes, int n_in,
                              void* d_out, int out_size, void* d_ws, size_t ws_size,
                              hipStream_t stream) {
    const float* x  = (const float*)d_in[0];
    const float* kc = (const float*)d_in[1];
    const float* vc = (const float*)d_in[2];
    const float* Wq = (const float*)d_in[3];
    const float* Wo = (const float*)d_in[4];
    float* out = (float*)d_out;

    char* ws = (char*)d_ws;
    unsigned short* Xb  = (unsigned short*)(ws);              // 33,554,432 B (reused as O)
    unsigned short* Qb  = (unsigned short*)(ws + 33554432);   // 33,554,432 B
    unsigned short* Wqb = (unsigned short*)(ws + 67108864);   //  8,388,608 B
    unsigned short* Wob = (unsigned short*)(ws + 75497472);   //  8,388,608 B
    unsigned short* Kwb = (unsigned short*)(ws + 83886080);   //  2,097,152 B
    unsigned short* Vtb = (unsigned short*)(ws + 85983232);   //  2,097,152 B

    cvt_bf16<<<16384, 256, 0, stream>>>(x,  Xb,  4194304);
    cvt_bf16<<<4096,  256, 0, stream>>>(Wq, Wqb, 1048576);
    cvt_bf16<<<4096,  256, 0, stream>>>(Wo, Wob, 1048576);
    prep_k<<<1024, 256, 0, stream>>>(kc, Kwb);
    prep_v<<<256, 256, 0, stream>>>(vc, Vtb);

    gemm_bt<0><<<1024, 256, 0, stream>>>(Xb, Wqb, nullptr, Qb);   // Q + RoPE (pre-scaled)
    attn<<<4096, 256, 0, stream>>>(Qb, Kwb, Vtb, Xb);             // O -> Xb
    gemm_bt<1><<<1024, 256, 0, stream>>>(Xb, Wob, out, nullptr);  // out proj
}

// Round 3
// 511.264 us; speedup vs baseline: 1.0941x; 1.0013x over previous
//
#include <hip/hip_runtime.h>
#include <math.h>

typedef __attribute__((ext_vector_type(8))) short short8;
typedef __attribute__((ext_vector_type(4))) float floatx4;
typedef __attribute__((ext_vector_type(4))) unsigned int uintx4;
typedef __attribute__((ext_vector_type(2))) unsigned int uintx2;

#define MFMA16(a, b, c) __builtin_amdgcn_mfma_f32_16x16x32_bf16((a), (b), (c), 0, 0, 0)

// log2(e) * (1/sqrt(64)) — folded into Q so attention works in exp2 domain
#define QSCALE 0.18033688011112042f

__device__ __forceinline__ unsigned short f2bf(float x) {
    unsigned int u = __float_as_uint(x);
    u += 0x7fffu + ((u >> 16) & 1u);   // round-to-nearest-even
    return (unsigned short)(u >> 16);
}

__device__ __forceinline__ short8 lds8(const unsigned short* p) {
    return *reinterpret_cast<const short8*>(p);
}

// async global->LDS, 16B per lane; LDS dest = wave-uniform base + lane*16
__device__ __forceinline__ void g2l16(const unsigned short* g, unsigned short* l) {
    __builtin_amdgcn_global_load_lds(
        (const __attribute__((address_space(1))) unsigned int*)g,
        (__attribute__((address_space(3))) unsigned int*)l,
        16, 0, 0);
}

// pack two f32 -> bf16x2 dword (RNE): low = a, high = b
__device__ __forceinline__ unsigned int cvtpk(float a, float b) {
    unsigned int r;
    asm("v_cvt_pk_bf16_f32 %0, %1, %2" : "=v"(r) : "v"(a), "v"(b));
    return r;
}

// swap lanes[32:63] of a with lanes[0:31] of b (both modified)
__device__ __forceinline__ void pl32swap(unsigned int& a, unsigned int& b) {
    asm("v_permlane32_swap_b32 %0, %1" : "+v"(a), "+v"(b));
}

// swap odd 16-lane groups of a with even 16-lane groups of b (both modified)
__device__ __forceinline__ void pl16swap(unsigned int& a, unsigned int& b) {
    asm("v_permlane16_swap_b32 %0, %1" : "+v"(a), "+v"(b));
}

// ---------------- prep: fp32 -> bf16 convert (vectorized) ----------------
__global__ void cvt_bf16(const float* __restrict__ src, unsigned short* __restrict__ dst, int n4) {
    int i = blockIdx.x * blockDim.x + threadIdx.x;
    if (i >= n4) return;
    float4 v = reinterpret_cast<const float4*>(src)[i];
    ushort4 o;
    o.x = f2bf(v.x); o.y = f2bf(v.y); o.z = f2bf(v.z); o.w = f2bf(v.w);
    reinterpret_cast<ushort4*>(dst)[i] = o;
}

// ---------------- prep: K window convert (coalesced both sides) ----------------
__global__ void prep_k(const float* __restrict__ kc, unsigned short* __restrict__ Kw) {
    int i = blockIdx.x * blockDim.x + threadIdx.x;   // 0 .. 262143
    int d4  = (i & 15) * 4;
    int s   = (i >> 4) & 1023;
    int bkv = i >> 14;
    size_t src = ((size_t)bkv * 4096 + 3072 + s) * 64 + d4;
    float4 kv = *reinterpret_cast<const float4*>(kc + src);
    ushort4 ko;
    ko.x = f2bf(kv.x); ko.y = f2bf(kv.y); ko.z = f2bf(kv.z); ko.w = f2bf(kv.w);
    *reinterpret_cast<ushort4*>(Kw + ((size_t)bkv * 1024 + s) * 64 + d4) = ko;
}

// ---------------- prep: V window transpose via LDS tile ----------------
__global__ void prep_v(const float* __restrict__ vc, unsigned short* __restrict__ Vt) {
    __shared__ unsigned short tl[64][72];
    const int bkv = blockIdx.x >> 4;
    const int s0  = (blockIdx.x & 15) * 64;
    const int t   = threadIdx.x;
    const int sl  = t >> 2;
    const int dq  = (t & 3) * 16;
    const float* src = vc + ((size_t)bkv * 4096 + 3072 + s0 + sl) * 64 + dq;
    float4 v0 = reinterpret_cast<const float4*>(src)[0];
    float4 v1 = reinterpret_cast<const float4*>(src)[1];
    float4 v2 = reinterpret_cast<const float4*>(src)[2];
    float4 v3 = reinterpret_cast<const float4*>(src)[3];
    tl[dq +  0][sl] = f2bf(v0.x); tl[dq +  1][sl] = f2bf(v0.y);
    tl[dq +  2][sl] = f2bf(v0.z); tl[dq +  3][sl] = f2bf(v0.w);
    tl[dq +  4][sl] = f2bf(v1.x); tl[dq +  5][sl] = f2bf(v1.y);
    tl[dq +  6][sl] = f2bf(v1.z); tl[dq +  7][sl] = f2bf(v1.w);
    tl[dq +  8][sl] = f2bf(v2.x); tl[dq +  9][sl] = f2bf(v2.y);
    tl[dq + 10][sl] = f2bf(v2.z); tl[dq + 11][sl] = f2bf(v2.w);
    tl[dq + 12][sl] = f2bf(v3.x); tl[dq + 13][sl] = f2bf(v3.y);
    tl[dq + 14][sl] = f2bf(v3.z); tl[dq + 15][sl] = f2bf(v3.w);
    __syncthreads();
    const int dl = t >> 2;
    const int sc = (t & 3) * 16;
    unsigned short* dst = Vt + ((size_t)bkv * 64 + dl) * 1024 + s0 + sc;
    short8 x0 = *reinterpret_cast<const short8*>(&tl[dl][sc]);
    short8 x1 = *reinterpret_cast<const short8*>(&tl[dl][sc + 8]);
    *reinterpret_cast<short8*>(dst)     = x0;
    *reinterpret_cast<short8*>(dst + 8) = x1;
}

// ---------------- bf16 MFMA GEMM (m97 structure): C = A[M,K] * Bt[N,K]^T ----------------
// EPI=0: fused RoPE epilogue with per-block LDS cos/sin table (128 t x 32 d2,
// padded stride 33 to break 4-way bank aliasing across quads).
template <int EPI>
__global__ __launch_bounds__(256)
void gemm_bt(const unsigned short* __restrict__ A,
             const unsigned short* __restrict__ Bt,
             float* __restrict__ Cf,
             unsigned short* __restrict__ Cb) {
    constexpr int K = 2048;
    __shared__ unsigned short As[128 * 32];
    __shared__ unsigned short Bs[128 * 32];
    __shared__ float2 tab[EPI == 0 ? 128 * 33 : 1];

    const int tid  = threadIdx.x;
    const int lane = tid & 63;
    const int l15  = lane & 15;
    const int quad = lane >> 4;
    const int wid  = tid >> 6;
    const int wm   = (wid & 1) * 64;
    const int wn   = (wid >> 1) * 64;

    const int bn = blockIdx.x & 15;
    const int bm = blockIdx.x >> 4;

    if (EPI == 0) {
        // fill RoPE table: t = (bm&31)*128 + tl, tl in [0,128), d2 in [0,32)
        const int t0 = (bm & 31) * 128;
        for (int e = tid; e < 4096; e += 256) {
            int tl = e >> 5, d2 = e & 31;
            float f = (float)(t0 + tl) * exp2f(-(float)d2 * 0.41524101186092f);
            float sn, cs; __sincosf(f, &sn, &cs);
            tab[tl * 33 + d2] = make_float2(cs, sn);
        }
        // visibility: established by the first __syncthreads in the k-loop
    }

    const int row0 = tid >> 2;
    const int kc8  = (tid & 3) * 8;
    const unsigned short* Ag0 = A  + (size_t)(bm * 128 + row0) * K + kc8;
    const unsigned short* Ag1 = Ag0 + (size_t)64 * K;
    const unsigned short* Bg0 = Bt + (size_t)(bn * 128 + row0) * K + kc8;
    const unsigned short* Bg1 = Bg0 + (size_t)64 * K;
    unsigned short* AsW0 = As + wid * 512;
    unsigned short* AsW1 = As + 2048 + wid * 512;
    unsigned short* BsW0 = Bs + wid * 512;
    unsigned short* BsW1 = Bs + 2048 + wid * 512;

    floatx4 c00 = {0,0,0,0}, c01 = {0,0,0,0}, c02 = {0,0,0,0}, c03 = {0,0,0,0};
    floatx4 c10 = {0,0,0,0}, c11 = {0,0,0,0}, c12 = {0,0,0,0}, c13 = {0,0,0,0};
    floatx4 c20 = {0,0,0,0}, c21 = {0,0,0,0}, c22 = {0,0,0,0}, c23 = {0,0,0,0};
    floatx4 c30 = {0,0,0,0}, c31 = {0,0,0,0}, c32 = {0,0,0,0}, c33 = {0,0,0,0};

    for (int k0 = 0; k0 < K; k0 += 32) {
        __syncthreads();
        g2l16(Ag0 + k0, AsW0);
        g2l16(Ag1 + k0, AsW1);
        g2l16(Bg0 + k0, BsW0);
        g2l16(Bg1 + k0, BsW1);
        __syncthreads();

        short8 a0 = lds8(&As[(wm +  0 + l15) * 32 + quad * 8]);
        short8 a1 = lds8(&As[(wm + 16 + l15) * 32 + quad * 8]);
        short8 a2 = lds8(&As[(wm + 32 + l15) * 32 + quad * 8]);
        short8 a3 = lds8(&As[(wm + 48 + l15) * 32 + quad * 8]);
        short8 b0 = lds8(&Bs[(wn +  0 + l15) * 32 + quad * 8]);
        short8 b1 = lds8(&Bs[(wn + 16 + l15) * 32 + quad * 8]);
        short8 b2 = lds8(&Bs[(wn + 32 + l15) * 32 + quad * 8]);
        short8 b3 = lds8(&Bs[(wn + 48 + l15) * 32 + quad * 8]);

        c00 = MFMA16(a0, b0, c00); c01 = MFMA16(a0, b1, c01);
        c02 = MFMA16(a0, b2, c02); c03 = MFMA16(a0, b3, c03);
        c10 = MFMA16(a1, b0, c10); c11 = MFMA16(a1, b1, c11);
        c12 = MFMA16(a1, b2, c12); c13 = MFMA16(a1, b3, c13);
        c20 = MFMA16(a2, b0, c20); c21 = MFMA16(a2, b1, c21);
        c22 = MFMA16(a2, b2, c22); c23 = MFMA16(a2, b3, c23);
        c30 = MFMA16(a3, b0, c30); c31 = MFMA16(a3, b1, c31);
        c32 = MFMA16(a3, b2, c32); c33 = MFMA16(a3, b3, c33);
    }

#define EPI_TILE(i, j, C) do {                                                  \
    _Pragma("unroll")                                                           \
    for (int r = 0; r < 4; ++r) {                                               \
        int row = bm * 128 + wm + (i) * 16 + quad * 4 + r;                      \
        int col = bn * 128 + wn + (j) * 16 + l15;                               \
        float v = (C)[r];                                                       \
        if (EPI == 0) {                                                         \
            float p = __shfl_xor(v, 1);                                         \
            int t = row & 4095, b = row >> 12;                                  \
            int hh = col >> 6, d = col & 63;                                    \
            int tl = wm + (i) * 16 + quad * 4 + r;                              \
            float2 cspair = tab[tl * 33 + (d >> 1)];                            \
            float o = (d & 1) ? (p * cspair.y + v * cspair.x)                   \
                              : (v * cspair.x - p * cspair.y);                  \
            o *= QSCALE;                                                        \
            float po = __shfl_xor(o, 1);                                        \
            if (!(lane & 1)) {                                                  \
                unsigned int pk = (unsigned int)f2bf(o) |                       \
                                  ((unsigned int)f2bf(po) << 16);               \
                *reinterpret_cast<unsigned int*>(                               \
                    Cb + ((size_t)((b * 32 + hh) * 4096 + t)) * 64 + d) = pk;   \
            }                                                                   \
        } else {                                                                \
            Cf[(size_t)row * 2048 + col] = v;                                   \
        }                                                                       \
    }                                                                           \
} while (0)

    EPI_TILE(0, 0, c00); EPI_TILE(0, 1, c01); EPI_TILE(0, 2, c02); EPI_TILE(0, 3, c03);
    EPI_TILE(1, 0, c10); EPI_TILE(1, 1, c11); EPI_TILE(1, 2, c12); EPI_TILE(1, 3, c13);
    EPI_TILE(2, 0, c20); EPI_TILE(2, 1, c21); EPI_TILE(2, 2, c22); EPI_TILE(2, 3, c23);
    EPI_TILE(3, 0, c30); EPI_TILE(3, 1, c31); EPI_TILE(3, 2, c32); EPI_TILE(3, 3, c33);
#undef EPI_TILE
}

// ---------------- flash attention over 1024-key window ----------------
// Swapped-operand form (T12): S^T = mfma(K,Q); P repack fully in-register
// (cvt_pk_bf16 + permlane swaps); PV as O^T = mfma(V^T, P^T).
// This round: per-query max (quad-reduce, 2 shuffles instead of 6-wide
// butterfly) + defer-max (T13, THR=8) so the O-rescale is skipped on almost
// every tile; max3-friendly local max tree.
__global__ __launch_bounds__(256, 5)
void attn(const unsigned short* __restrict__ Q,
          const unsigned short* __restrict__ Kw,
          const unsigned short* __restrict__ Vt,
          unsigned short* __restrict__ O) {
    const int blk   = blockIdx.x;
    const int qtile = blk & 63;
    const int bh    = blk >> 6;
    const int h     = bh & 31;
    const int b     = bh >> 5;
    const int kvh   = h >> 2;

    const int tid  = threadIdx.x;
    const int lane = tid & 63;
    const int l15  = lane & 15;
    const int quad = lane >> 4;
    const int wid  = tid >> 6;
    const int qt0  = qtile * 64 + wid * 16;

    const unsigned short* Qp = Q  + ((size_t)bh * 4096 + qt0) * 64;
    const unsigned short* Kp = Kw + (size_t)(b * 8 + kvh) * 1024 * 64;
    const unsigned short* Vp = Vt + (size_t)(b * 8 + kvh) * 64 * 1024;

    // [buf][frag(8) * 512 + lane*8]; frag (c*2+half) for K, (j*2+shalf) for V
    __shared__ unsigned short Ks[2][4096];
    __shared__ unsigned short Vs[2][4096];

    short8 qa0 = lds8(&Qp[l15 * 64 + quad * 8]);
    short8 qa1 = lds8(&Qp[l15 * 64 + 32 + quad * 8]);

    // staging source addrs: wave w stages K frag c=w (both halves), V frag j=w
    const unsigned short* gK = Kp + (size_t)(wid * 16 + l15) * 64 + quad * 8;
    const unsigned short* gV = Vp + (size_t)(wid * 16 + l15) * 1024 + quad * 8;

    const int ntiles = (qtile < 15 ? qtile + 1 : 16);       // block-uniform
    const int nkW    = (qt0 + 16 < 1024) ? qt0 + 16 : 1024; // per-wave keys
    const bool diag  = (qtile < 16);

    // prefetch tile 0
    g2l16(gK,      &Ks[0][wid * 1024]);
    g2l16(gK + 32, &Ks[0][wid * 1024 + 512]);
    g2l16(gV,      &Vs[0][wid * 1024]);
    g2l16(gV + 32, &Vs[0][wid * 1024 + 512]);

    floatx4 o0 = {0,0,0,0}, o1 = {0,0,0,0}, o2 = {0,0,0,0}, o3 = {0,0,0,0};
    float Lq = 0.f;
    float m = -INFINITY;

    for (int it = 0; it < ntiles; ++it) {
        __syncthreads();                         // staging of tile `it` complete
        const int cur = it & 1;
        if (it + 1 < ntiles) {                   // prefetch next into other buffer
            const int nxt = cur ^ 1;
            const unsigned short* gKn = gK + (it + 1) * 4096;
            const unsigned short* gVn = gV + (it + 1) * 64;
            g2l16(gKn,      &Ks[nxt][wid * 1024]);
            g2l16(gKn + 32, &Ks[nxt][wid * 1024 + 512]);
            g2l16(gVn,      &Vs[nxt][wid * 1024]);
            g2l16(gVn + 32, &Vs[nxt][wid * 1024 + 512]);
        }
        const int s0 = it << 6;
        const unsigned short* Kc = Ks[cur];
        const unsigned short* Vc = Vs[cur];

        // S^T = K·Q^T: lane holds S[key = s0 + c*16 + quad*4 + r][query = qt0 + l15]
        floatx4 sS[4];
#pragma unroll
        for (int c = 0; c < 4; ++c) {
            floatx4 z = {0, 0, 0, 0};
            z = MFMA16(lds8(Kc + c * 1024 + lane * 8), qa0, z);
            z = MFMA16(lds8(Kc + c * 1024 + 512 + lane * 8), qa1, z);
            sS[c] = z;
        }

        const bool last = (it == ntiles - 1);
        bool skipHi = false;
        if (last && diag) {                      // diagonal tile: causal mask
#pragma unroll
            for (int c = 0; c < 4; ++c)
#pragma unroll
                for (int r = 0; r < 4; ++r)
                    if (s0 + c * 16 + quad * 4 + r > qt0 + l15) sS[c][r] = -INFINITY;
            skipHi = (nkW - s0 <= 32);
        }

        // per-query tile max: max3 tree + quad reduce (keys live on quad bits)
        float t0 = fmaxf(fmaxf(sS[0][0], sS[0][1]), fmaxf(sS[0][2], sS[0][3]));
        float t1 = fmaxf(fmaxf(sS[1][0], sS[1][1]), fmaxf(sS[1][2], sS[1][3]));
        float t2 = fmaxf(fmaxf(sS[2][0], sS[2][1]), fmaxf(sS[2][2], sS[2][3]));
        float t3 = fmaxf(fmaxf(sS[3][0], sS[3][1]), fmaxf(sS[3][2], sS[3][3]));
        float mx = fmaxf(fmaxf(t0, t1), fmaxf(t2, t3));
        mx = fmaxf(mx, __shfl_xor(mx, 16));
        mx = fmaxf(mx, __shfl_xor(mx, 32));      // quad-uniform per query l15

        // defer-max (T13): only rescale when tile max exceeds m by > 8
        // (P then bounded by 2^8 = 256 — fine for bf16 P and f32 L/O accum)
        if (!__all(mx <= m + 8.0f)) {
            const float mn = fmaxf(m, mx);       // quad-uniform per query
            const float alpha = exp2f(m - mn);   // m=-inf first tile -> alpha=0
            m = mn;
            o0 *= alpha; o1 *= alpha; o2 *= alpha; o3 *= alpha;
            Lq *= alpha;
        }

        float p[4][4];
#pragma unroll
        for (int c = 0; c < 4; ++c)
#pragma unroll
            for (int r = 0; r < 4; ++r) p[c][r] = exp2f(sS[c][r] - m);
        Lq += ((p[0][0] + p[0][1] + p[0][2] + p[0][3]) + (p[1][0] + p[1][1] + p[1][2] + p[1][3]))
            + ((p[2][0] + p[2][1] + p[2][2] + p[2][3]) + (p[3][0] + p[3][1] + p[3][2] + p[3][3]));

        // in-register P repack: keys 0-31 (chunks 0,1) -> pa_lo
        unsigned int a0 = cvtpk(p[0][0], p[0][1]);
        unsigned int a1 = cvtpk(p[0][2], p[0][3]);
        unsigned int a2 = cvtpk(p[1][0], p[1][1]);
        unsigned int a3 = cvtpk(p[1][2], p[1][3]);
        pl32swap(a0, a2); pl32swap(a1, a3);
        pl16swap(a0, a2); pl16swap(a1, a3);
        uintx4 tlo = {a0, a1, a2, a3};
        short8 pa_lo = __builtin_bit_cast(short8, tlo);

        // O^T += V^T · P^T : A-frag = V^T (same LDS frags), B-frag = pa
        o0 = MFMA16(lds8(Vc + 0 * 512 + lane * 8), pa_lo, o0);
        o1 = MFMA16(lds8(Vc + 2 * 512 + lane * 8), pa_lo, o1);
        o2 = MFMA16(lds8(Vc + 4 * 512 + lane * 8), pa_lo, o2);
        o3 = MFMA16(lds8(Vc + 6 * 512 + lane * 8), pa_lo, o3);
        if (!skipHi) {
            // keys 32-63 (chunks 2,3) -> pa_hi
            unsigned int b0 = cvtpk(p[2][0], p[2][1]);
            unsigned int b1 = cvtpk(p[2][2], p[2][3]);
            unsigned int b2 = cvtpk(p[3][0], p[3][1]);
            unsigned int b3 = cvtpk(p[3][2], p[3][3]);
            pl32swap(b0, b2); pl32swap(b1, b3);
            pl16swap(b0, b2); pl16swap(b1, b3);
            uintx4 thi = {b0, b1, b2, b3};
            short8 pa_hi = __builtin_bit_cast(short8, thi);
            o0 = MFMA16(lds8(Vc + 1 * 512 + lane * 8), pa_hi, o0);
            o1 = MFMA16(lds8(Vc + 3 * 512 + lane * 8), pa_hi, o1);
            o2 = MFMA16(lds8(Vc + 5 * 512 + lane * 8), pa_hi, o2);
            o3 = MFMA16(lds8(Vc + 7 * 512 + lane * 8), pa_hi, o3);
        }
    }

    // Lq holds this lane's keys only; total = sum across quads
    Lq += __shfl_xor(Lq, 16);
    Lq += __shfl_xor(Lq, 32);
    const float inv = 1.f / Lq;

    // O^T layout: lane holds O[q = qt0+l15][d = j*16 + quad*4 + r] -> 8B stores
    unsigned short* Op = O + (size_t)b * 4096 * 2048 + (size_t)(qt0 + l15) * 2048
                           + h * 64 + quad * 4;
    uintx2 w0, w1, w2, w3;
    w0.x = cvtpk(o0[0] * inv, o0[1] * inv); w0.y = cvtpk(o0[2] * inv, o0[3] * inv);
    w1.x = cvtpk(o1[0] * inv, o1[1] * inv); w1.y = cvtpk(o1[2] * inv, o1[3] * inv);
    w2.x = cvtpk(o2[0] * inv, o2[1] * inv); w2.y = cvtpk(o2[2] * inv, o2[3] * inv);
    w3.x = cvtpk(o3[0] * inv, o3[1] * inv); w3.y = cvtpk(o3[2] * inv, o3[3] * inv);
    *reinterpret_cast<uintx2*>(Op)      = w0;
    *reinterpret_cast<uintx2*>(Op + 16) = w1;
    *reinterpret_cast<uintx2*>(Op + 32) = w2;
    *reinterpret_cast<uintx2*>(Op + 48) = w3;
}

// ---------------- launch ----------------
extern "C" void kernel_launch(void* const* d_in, const int* in_sizes, int n_in,
                              void* d_out, int out_size, void* d_ws, size_t ws_size,
                              hipStream_t stream) {
    const float* x  = (const float*)d_in[0];
    const float* kc = (const float*)d_in[1];
    const float* vc = (const float*)d_in[2];
    const float* Wq = (const float*)d_in[3];
    const float* Wo = (const float*)d_in[4];
    float* out = (float*)d_out;

    char* ws = (char*)d_ws;
    unsigned short* Xb  = (unsigned short*)(ws);              // 33,554,432 B (reused as O)
    unsigned short* Qb  = (unsigned short*)(ws + 33554432);   // 33,554,432 B
    unsigned short* Wqb = (unsigned short*)(ws + 67108864);   //  8,388,608 B
    unsigned short* Wob = (unsigned short*)(ws + 75497472);   //  8,388,608 B
    unsigned short* Kwb = (unsigned short*)(ws + 83886080);   //  2,097,152 B
    unsigned short* Vtb = (unsigned short*)(ws + 85983232);   //  2,097,152 B

    cvt_bf16<<<16384, 256, 0, stream>>>(x,  Xb,  4194304);
    cvt_bf16<<<4096,  256, 0, stream>>>(Wq, Wqb, 1048576);
    cvt_bf16<<<4096,  256, 0, stream>>>(Wo, Wob, 1048576);
    prep_k<<<1024, 256, 0, stream>>>(kc, Kwb);
    prep_v<<<256, 256, 0, stream>>>(vc, Vtb);

    gemm_bt<0><<<1024, 256, 0, stream>>>(Xb, Wqb, nullptr, Qb);   // Q + RoPE (pre-scaled)
    attn<<<4096, 256, 0, stream>>>(Qb, Kwb, Vtb, Xb);             // O -> Xb
    gemm_bt<1><<<1024, 256, 0, stream>>>(Xb, Wob, out, nullptr);  // out proj
}

// Round 4
// 505.783 us; speedup vs baseline: 1.1060x; 1.0108x over previous
//
#include <hip/hip_runtime.h>
#include <math.h>

typedef __attribute__((ext_vector_type(8))) short short8;
typedef __attribute__((ext_vector_type(4))) float floatx4;
typedef __attribute__((ext_vector_type(4))) unsigned int uintx4;
typedef __attribute__((ext_vector_type(2))) unsigned int uintx2;

#define MFMA16(a, b, c) __builtin_amdgcn_mfma_f32_16x16x32_bf16((a), (b), (c), 0, 0, 0)

// log2(e) * (1/sqrt(64)) — folded into Q so attention works in exp2 domain
#define QSCALE 0.18033688011112042f

__device__ __forceinline__ unsigned short f2bf(float x) {
    unsigned int u = __float_as_uint(x);
    u += 0x7fffu + ((u >> 16) & 1u);   // round-to-nearest-even
    return (unsigned short)(u >> 16);
}

__device__ __forceinline__ short8 lds8(const unsigned short* p) {
    return *reinterpret_cast<const short8*>(p);
}

// async global->LDS, 16B per lane; LDS dest = wave-uniform base + lane*16
__device__ __forceinline__ void g2l16(const unsigned short* g, unsigned short* l) {
    __builtin_amdgcn_global_load_lds(
        (const __attribute__((address_space(1))) unsigned int*)g,
        (__attribute__((address_space(3))) unsigned int*)l,
        16, 0, 0);
}

// pack two f32 -> bf16x2 dword (RNE): low = a, high = b
__device__ __forceinline__ unsigned int cvtpk(float a, float b) {
    unsigned int r;
    asm("v_cvt_pk_bf16_f32 %0, %1, %2" : "=v"(r) : "v"(a), "v"(b));
    return r;
}

// swap lanes[32:63] of a with lanes[0:31] of b (both modified)
__device__ __forceinline__ void pl32swap(unsigned int& a, unsigned int& b) {
    asm("v_permlane32_swap_b32 %0, %1" : "+v"(a), "+v"(b));
}

// swap odd 16-lane groups of a with even 16-lane groups of b (both modified)
__device__ __forceinline__ void pl16swap(unsigned int& a, unsigned int& b) {
    asm("v_permlane16_swap_b32 %0, %1" : "+v"(a), "+v"(b));
}

// ---------------- prep: fp32 -> bf16 convert (vectorized) ----------------
__global__ void cvt_bf16(const float* __restrict__ src, unsigned short* __restrict__ dst, int n4) {
    int i = blockIdx.x * blockDim.x + threadIdx.x;
    if (i >= n4) return;
    float4 v = reinterpret_cast<const float4*>(src)[i];
    ushort4 o;
    o.x = f2bf(v.x); o.y = f2bf(v.y); o.z = f2bf(v.z); o.w = f2bf(v.w);
    reinterpret_cast<ushort4*>(dst)[i] = o;
}

// ---------------- prep: K window convert (coalesced both sides) ----------------
__global__ void prep_k(const float* __restrict__ kc, unsigned short* __restrict__ Kw) {
    int i = blockIdx.x * blockDim.x + threadIdx.x;   // 0 .. 262143
    int d4  = (i & 15) * 4;
    int s   = (i >> 4) & 1023;
    int bkv = i >> 14;
    size_t src = ((size_t)bkv * 4096 + 3072 + s) * 64 + d4;
    float4 kv = *reinterpret_cast<const float4*>(kc + src);
    ushort4 ko;
    ko.x = f2bf(kv.x); ko.y = f2bf(kv.y); ko.z = f2bf(kv.z); ko.w = f2bf(kv.w);
    *reinterpret_cast<ushort4*>(Kw + ((size_t)bkv * 1024 + s) * 64 + d4) = ko;
}

// ---------------- prep: V window transpose via LDS tile ----------------
__global__ void prep_v(const float* __restrict__ vc, unsigned short* __restrict__ Vt) {
    __shared__ unsigned short tl[64][72];
    const int bkv = blockIdx.x >> 4;
    const int s0  = (blockIdx.x & 15) * 64;
    const int t   = threadIdx.x;
    const int sl  = t >> 2;
    const int dq  = (t & 3) * 16;
    const float* src = vc + ((size_t)bkv * 4096 + 3072 + s0 + sl) * 64 + dq;
    float4 v0 = reinterpret_cast<const float4*>(src)[0];
    float4 v1 = reinterpret_cast<const float4*>(src)[1];
    float4 v2 = reinterpret_cast<const float4*>(src)[2];
    float4 v3 = reinterpret_cast<const float4*>(src)[3];
    tl[dq +  0][sl] = f2bf(v0.x); tl[dq +  1][sl] = f2bf(v0.y);
    tl[dq +  2][sl] = f2bf(v0.z); tl[dq +  3][sl] = f2bf(v0.w);
    tl[dq +  4][sl] = f2bf(v1.x); tl[dq +  5][sl] = f2bf(v1.y);
    tl[dq +  6][sl] = f2bf(v1.z); tl[dq +  7][sl] = f2bf(v1.w);
    tl[dq +  8][sl] = f2bf(v2.x); tl[dq +  9][sl] = f2bf(v2.y);
    tl[dq + 10][sl] = f2bf(v2.z); tl[dq + 11][sl] = f2bf(v2.w);
    tl[dq + 12][sl] = f2bf(v3.x); tl[dq + 13][sl] = f2bf(v3.y);
    tl[dq + 14][sl] = f2bf(v3.z); tl[dq + 15][sl] = f2bf(v3.w);
    __syncthreads();
    const int dl = t >> 2;
    const int sc = (t & 3) * 16;
    unsigned short* dst = Vt + ((size_t)bkv * 64 + dl) * 1024 + s0 + sc;
    short8 x0 = *reinterpret_cast<const short8*>(&tl[dl][sc]);
    short8 x1 = *reinterpret_cast<const short8*>(&tl[dl][sc + 8]);
    *reinterpret_cast<short8*>(dst)     = x0;
    *reinterpret_cast<short8*>(dst + 8) = x1;
}

// ---------------- bf16 MFMA GEMM (m97 structure): C = A[M,K] * Bt[N,K]^T ----------------
// EPI=0: fused RoPE epilogue with per-block LDS cos/sin table (128 t x 32 d2,
// padded stride 33 to break 4-way bank aliasing across quads).
template <int EPI>
__global__ __launch_bounds__(256)
void gemm_bt(const unsigned short* __restrict__ A,
             const unsigned short* __restrict__ Bt,
             float* __restrict__ Cf,
             unsigned short* __restrict__ Cb) {
    constexpr int K = 2048;
    __shared__ unsigned short As[128 * 32];
    __shared__ unsigned short Bs[128 * 32];
    __shared__ float2 tab[EPI == 0 ? 128 * 33 : 1];

    const int tid  = threadIdx.x;
    const int lane = tid & 63;
    const int l15  = lane & 15;
    const int quad = lane >> 4;
    const int wid  = tid >> 6;
    const int wm   = (wid & 1) * 64;
    const int wn   = (wid >> 1) * 64;

    const int bn = blockIdx.x & 15;
    const int bm = blockIdx.x >> 4;

    if (EPI == 0) {
        // fill RoPE table: t = (bm&31)*128 + tl, tl in [0,128), d2 in [0,32)
        const int t0 = (bm & 31) * 128;
        for (int e = tid; e < 4096; e += 256) {
            int tl = e >> 5, d2 = e & 31;
            float f = (float)(t0 + tl) * exp2f(-(float)d2 * 0.41524101186092f);
            float sn, cs; __sincosf(f, &sn, &cs);
            tab[tl * 33 + d2] = make_float2(cs, sn);
        }
        // visibility: established by the first __syncthreads in the k-loop
    }

    const int row0 = tid >> 2;
    const int kc8  = (tid & 3) * 8;
    const unsigned short* Ag0 = A  + (size_t)(bm * 128 + row0) * K + kc8;
    const unsigned short* Ag1 = Ag0 + (size_t)64 * K;
    const unsigned short* Bg0 = Bt + (size_t)(bn * 128 + row0) * K + kc8;
    const unsigned short* Bg1 = Bg0 + (size_t)64 * K;
    unsigned short* AsW0 = As + wid * 512;
    unsigned short* AsW1 = As + 2048 + wid * 512;
    unsigned short* BsW0 = Bs + wid * 512;
    unsigned short* BsW1 = Bs + 2048 + wid * 512;

    floatx4 c00 = {0,0,0,0}, c01 = {0,0,0,0}, c02 = {0,0,0,0}, c03 = {0,0,0,0};
    floatx4 c10 = {0,0,0,0}, c11 = {0,0,0,0}, c12 = {0,0,0,0}, c13 = {0,0,0,0};
    floatx4 c20 = {0,0,0,0}, c21 = {0,0,0,0}, c22 = {0,0,0,0}, c23 = {0,0,0,0};
    floatx4 c30 = {0,0,0,0}, c31 = {0,0,0,0}, c32 = {0,0,0,0}, c33 = {0,0,0,0};

    for (int k0 = 0; k0 < K; k0 += 32) {
        __syncthreads();
        g2l16(Ag0 + k0, AsW0);
        g2l16(Ag1 + k0, AsW1);
        g2l16(Bg0 + k0, BsW0);
        g2l16(Bg1 + k0, BsW1);
        __syncthreads();

        short8 a0 = lds8(&As[(wm +  0 + l15) * 32 + quad * 8]);
        short8 a1 = lds8(&As[(wm + 16 + l15) * 32 + quad * 8]);
        short8 a2 = lds8(&As[(wm + 32 + l15) * 32 + quad * 8]);
        short8 a3 = lds8(&As[(wm + 48 + l15) * 32 + quad * 8]);
        short8 b0 = lds8(&Bs[(wn +  0 + l15) * 32 + quad * 8]);
        short8 b1 = lds8(&Bs[(wn + 16 + l15) * 32 + quad * 8]);
        short8 b2 = lds8(&Bs[(wn + 32 + l15) * 32 + quad * 8]);
        short8 b3 = lds8(&Bs[(wn + 48 + l15) * 32 + quad * 8]);

        c00 = MFMA16(a0, b0, c00); c01 = MFMA16(a0, b1, c01);
        c02 = MFMA16(a0, b2, c02); c03 = MFMA16(a0, b3, c03);
        c10 = MFMA16(a1, b0, c10); c11 = MFMA16(a1, b1, c11);
        c12 = MFMA16(a1, b2, c12); c13 = MFMA16(a1, b3, c13);
        c20 = MFMA16(a2, b0, c20); c21 = MFMA16(a2, b1, c21);
        c22 = MFMA16(a2, b2, c22); c23 = MFMA16(a2, b3, c23);
        c30 = MFMA16(a3, b0, c30); c31 = MFMA16(a3, b1, c31);
        c32 = MFMA16(a3, b2, c32); c33 = MFMA16(a3, b3, c33);
    }

#define EPI_TILE(i, j, C) do {                                                  \
    _Pragma("unroll")                                                           \
    for (int r = 0; r < 4; ++r) {                                               \
        int row = bm * 128 + wm + (i) * 16 + quad * 4 + r;                      \
        int col = bn * 128 + wn + (j) * 16 + l15;                               \
        float v = (C)[r];                                                       \
        if (EPI == 0) {                                                         \
            float p = __shfl_xor(v, 1);                                         \
            int t = row & 4095, b = row >> 12;                                  \
            int hh = col >> 6, d = col & 63;                                    \
            int tl = wm + (i) * 16 + quad * 4 + r;                              \
            float2 cspair = tab[tl * 33 + (d >> 1)];                            \
            float o = (d & 1) ? (p * cspair.y + v * cspair.x)                   \
                              : (v * cspair.x - p * cspair.y);                  \
            o *= QSCALE;                                                        \
            float po = __shfl_xor(o, 1);                                        \
            if (!(lane & 1)) {                                                  \
                unsigned int pk = (unsigned int)f2bf(o) |                       \
                                  ((unsigned int)f2bf(po) << 16);               \
                *reinterpret_cast<unsigned int*>(                               \
                    Cb + ((size_t)((b * 32 + hh) * 4096 + t)) * 64 + d) = pk;   \
            }                                                                   \
        } else {                                                                \
            Cf[(size_t)row * 2048 + col] = v;                                   \
        }                                                                       \
    }                                                                           \
} while (0)

    EPI_TILE(0, 0, c00); EPI_TILE(0, 1, c01); EPI_TILE(0, 2, c02); EPI_TILE(0, 3, c03);
    EPI_TILE(1, 0, c10); EPI_TILE(1, 1, c11); EPI_TILE(1, 2, c12); EPI_TILE(1, 3, c13);
    EPI_TILE(2, 0, c20); EPI_TILE(2, 1, c21); EPI_TILE(2, 2, c22); EPI_TILE(2, 3, c23);
    EPI_TILE(3, 0, c30); EPI_TILE(3, 1, c31); EPI_TILE(3, 2, c32); EPI_TILE(3, 3, c33);
#undef EPI_TILE
}

// ---------------- flash attention over 1024-key window ----------------
// Swapped-operand form (T12) + in-register P repack. This round: 512-thread /
// 8-wave blocks covering 128 queries. K/V LDS tiles (32 KiB, double-buffered)
// are shared by 8 waves instead of 4: occupancy cap rises from 20 to 32
// waves/CU (LDS 160/32=5 -> wave-cap 4 blocks x 8 waves = 100%), per-wave
// staging halves (1 K-frag + 1 V-frag), K/V HBM fetch per query halves.
// Waves whose query range ends before tile `it` skip compute via the
// wave-uniform `it < ntW` guard; barriers and staging stay block-uniform.
__global__ __launch_bounds__(512, 8)
void attn(const unsigned short* __restrict__ Q,
          const unsigned short* __restrict__ Kw,
          const unsigned short* __restrict__ Vt,
          unsigned short* __restrict__ O) {
    const int blk  = blockIdx.x;
    const int qblk = blk & 31;          // 32 blocks of 128 queries
    const int bh   = blk >> 5;
    const int h    = bh & 31;
    const int b    = bh >> 5;
    const int kvh  = h >> 2;

    const int tid  = threadIdx.x;
    const int lane = tid & 63;
    const int l15  = lane & 15;
    const int quad = lane >> 4;
    const int wid  = tid >> 6;          // 0..7
    const int qt0  = qblk * 128 + wid * 16;

    const unsigned short* Qp = Q  + ((size_t)bh * 4096 + qt0) * 64;
    const unsigned short* Kp = Kw + (size_t)(b * 8 + kvh) * 1024 * 64;
    const unsigned short* Vp = Vt + (size_t)(b * 8 + kvh) * 64 * 1024;

    // [buf][frag(8) * 512 + lane*8]; frag (c*2+half) for K, (j*2+shalf) for V
    __shared__ unsigned short Ks[2][4096];
    __shared__ unsigned short Vs[2][4096];

    short8 qa0 = lds8(&Qp[l15 * 64 + quad * 8]);
    short8 qa1 = lds8(&Qp[l15 * 64 + 32 + quad * 8]);

    // staging: wave w stages K frag f=w (chunk c=w>>1, k-half w&1) and
    // V frag f=w (d-group j=w>>1, key-half w&1)
    const unsigned short* gK = Kp + (size_t)((wid >> 1) * 16 + l15) * 64
                                  + (wid & 1) * 32 + quad * 8;
    const unsigned short* gV = Vp + (size_t)((wid >> 1) * 16 + l15) * 1024
                                  + (wid & 1) * 32 + quad * 8;
    unsigned short* sK0 = &Ks[0][wid * 512];
    unsigned short* sK1 = &Ks[1][wid * 512];
    unsigned short* sV0 = &Vs[0][wid * 512];
    unsigned short* sV1 = &Vs[1][wid * 512];

    const int ntiles = (qblk < 7 ? 2 * qblk + 2 : 16);      // block-uniform
    const int nkW    = (qt0 + 16 < 1024) ? qt0 + 16 : 1024; // per-wave keys
    const int ntW    = (nkW + 63) >> 6;                     // wave's tile count
    const bool diagW = (qt0 < 1024);

    // prefetch tile 0
    g2l16(gK, sK0);
    g2l16(gV, sV0);

    floatx4 o0 = {0,0,0,0}, o1 = {0,0,0,0}, o2 = {0,0,0,0}, o3 = {0,0,0,0};
    float Lq = 0.f;
    float m = -INFINITY;

    for (int it = 0; it < ntiles; ++it) {
        __syncthreads();                         // staging of tile `it` complete
        const int cur = it & 1;
        if (it + 1 < ntiles) {                   // prefetch next into other buffer
            g2l16(gK + (it + 1) * 4096, cur ? sK0 : sK1);
            g2l16(gV + (it + 1) * 64,   cur ? sV0 : sV1);
        }
        if (it >= ntW) continue;                 // wave done (barriers stay uniform)
        const int s0 = it << 6;
        const unsigned short* Kc = Ks[cur];
        const unsigned short* Vc = Vs[cur];

        // S^T = K·Q^T: lane holds S[key = s0 + c*16 + quad*4 + r][query = qt0 + l15]
        floatx4 sS[4];
#pragma unroll
        for (int c = 0; c < 4; ++c) {
            floatx4 z = {0, 0, 0, 0};
            z = MFMA16(lds8(Kc + c * 1024 + lane * 8), qa0, z);
            z = MFMA16(lds8(Kc + c * 1024 + 512 + lane * 8), qa1, z);
            sS[c] = z;
        }

        const bool last = (it == ntW - 1);
        bool skipHi = false;
        if (last && diagW) {                     // diagonal tile: causal mask
#pragma unroll
            for (int c = 0; c < 4; ++c)
#pragma unroll
                for (int r = 0; r < 4; ++r)
                    if (s0 + c * 16 + quad * 4 + r > qt0 + l15) sS[c][r] = -INFINITY;
            skipHi = (nkW - s0 <= 32);
        }

        // per-query tile max: max3 tree + quad reduce (keys live on quad bits)
        float t0 = fmaxf(fmaxf(sS[0][0], sS[0][1]), fmaxf(sS[0][2], sS[0][3]));
        float t1 = fmaxf(fmaxf(sS[1][0], sS[1][1]), fmaxf(sS[1][2], sS[1][3]));
        float t2 = fmaxf(fmaxf(sS[2][0], sS[2][1]), fmaxf(sS[2][2], sS[2][3]));
        float t3 = fmaxf(fmaxf(sS[3][0], sS[3][1]), fmaxf(sS[3][2], sS[3][3]));
        float mx = fmaxf(fmaxf(t0, t1), fmaxf(t2, t3));
        mx = fmaxf(mx, __shfl_xor(mx, 16));
        mx = fmaxf(mx, __shfl_xor(mx, 32));      // quad-uniform per query l15

        // defer-max (T13): only rescale when tile max exceeds m by > 8
        // (P then bounded by 2^8 = 256 — fine for bf16 P and f32 L/O accum)
        if (!__all(mx <= m + 8.0f)) {
            const float mn = fmaxf(m, mx);       // quad-uniform per query
            const float alpha = exp2f(m - mn);   // m=-inf first tile -> alpha=0
            m = mn;
            o0 *= alpha; o1 *= alpha; o2 *= alpha; o3 *= alpha;
            Lq *= alpha;
        }

        float p[4][4];
#pragma unroll
        for (int c = 0; c < 4; ++c)
#pragma unroll
            for (int r = 0; r < 4; ++r) p[c][r] = exp2f(sS[c][r] - m);
        Lq += ((p[0][0] + p[0][1] + p[0][2] + p[0][3]) + (p[1][0] + p[1][1] + p[1][2] + p[1][3]))
            + ((p[2][0] + p[2][1] + p[2][2] + p[2][3]) + (p[3][0] + p[3][1] + p[3][2] + p[3][3]));

        // in-register P repack: keys 0-31 (chunks 0,1) -> pa_lo
        unsigned int a0 = cvtpk(p[0][0], p[0][1]);
        unsigned int a1 = cvtpk(p[0][2], p[0][3]);
        unsigned int a2 = cvtpk(p[1][0], p[1][1]);
        unsigned int a3 = cvtpk(p[1][2], p[1][3]);
        pl32swap(a0, a2); pl32swap(a1, a3);
        pl16swap(a0, a2); pl16swap(a1, a3);
        uintx4 tlo = {a0, a1, a2, a3};
        short8 pa_lo = __builtin_bit_cast(short8, tlo);

        // O^T += V^T · P^T : A-frag = V^T (same LDS frags), B-frag = pa
        o0 = MFMA16(lds8(Vc + 0 * 512 + lane * 8), pa_lo, o0);
        o1 = MFMA16(lds8(Vc + 2 * 512 + lane * 8), pa_lo, o1);
        o2 = MFMA16(lds8(Vc + 4 * 512 + lane * 8), pa_lo, o2);
        o3 = MFMA16(lds8(Vc + 6 * 512 + lane * 8), pa_lo, o3);
        if (!skipHi) {
            // keys 32-63 (chunks 2,3) -> pa_hi
            unsigned int b0 = cvtpk(p[2][0], p[2][1]);
            unsigned int b1 = cvtpk(p[2][2], p[2][3]);
            unsigned int b2 = cvtpk(p[3][0], p[3][1]);
            unsigned int b3 = cvtpk(p[3][2], p[3][3]);
            pl32swap(b0, b2); pl32swap(b1, b3);
            pl16swap(b0, b2); pl16swap(b1, b3);
            uintx4 thi = {b0, b1, b2, b3};
            short8 pa_hi = __builtin_bit_cast(short8, thi);
            o0 = MFMA16(lds8(Vc + 1 * 512 + lane * 8), pa_hi, o0);
            o1 = MFMA16(lds8(Vc + 3 * 512 + lane * 8), pa_hi, o1);
            o2 = MFMA16(lds8(Vc + 5 * 512 + lane * 8), pa_hi, o2);
            o3 = MFMA16(lds8(Vc + 7 * 512 + lane * 8), pa_hi, o3);
        }
    }

    // Lq holds this lane's keys only; total = sum across quads
    Lq += __shfl_xor(Lq, 16);
    Lq += __shfl_xor(Lq, 32);
    const float inv = 1.f / Lq;

    // O^T layout: lane holds O[q = qt0+l15][d = j*16 + quad*4 + r] -> 8B stores
    unsigned short* Op = O + (size_t)b * 4096 * 2048 + (size_t)(qt0 + l15) * 2048
                           + h * 64 + quad * 4;
    uintx2 w0, w1, w2, w3;
    w0.x = cvtpk(o0[0] * inv, o0[1] * inv); w0.y = cvtpk(o0[2] * inv, o0[3] * inv);
    w1.x = cvtpk(o1[0] * inv, o1[1] * inv); w1.y = cvtpk(o1[2] * inv, o1[3] * inv);
    w2.x = cvtpk(o2[0] * inv, o2[1] * inv); w2.y = cvtpk(o2[2] * inv, o2[3] * inv);
    w3.x = cvtpk(o3[0] * inv, o3[1] * inv); w3.y = cvtpk(o3[2] * inv, o3[3] * inv);
    *reinterpret_cast<uintx2*>(Op)      = w0;
    *reinterpret_cast<uintx2*>(Op + 16) = w1;
    *reinterpret_cast<uintx2*>(Op + 32) = w2;
    *reinterpret_cast<uintx2*>(Op + 48) = w3;
}

// ---------------- launch ----------------
extern "C" void kernel_launch(void* const* d_in, const int* in_sizes, int n_in,
                              void* d_out, int out_size, void* d_ws, size_t ws_size,
                              hipStream_t stream) {
    const float* x  = (const float*)d_in[0];
    const float* kc = (const float*)d_in[1];
    const float* vc = (const float*)d_in[2];
    const float* Wq = (const float*)d_in[3];
    const float* Wo = (const float*)d_in[4];
    float* out = (float*)d_out;

    char* ws = (char*)d_ws;
    unsigned short* Xb  = (unsigned short*)(ws);              // 33,554,432 B (reused as O)
    unsigned short* Qb  = (unsigned short*)(ws + 33554432);   // 33,554,432 B
    unsigned short* Wqb = (unsigned short*)(ws + 67108864);   //  8,388,608 B
    unsigned short* Wob = (unsigned short*)(ws + 75497472);   //  8,388,608 B
    unsigned short* Kwb = (unsigned short*)(ws + 83886080);   //  2,097,152 B
    unsigned short* Vtb = (unsigned short*)(ws + 85983232);   //  2,097,152 B

    cvt_bf16<<<16384, 256, 0, stream>>>(x,  Xb,  4194304);
    cvt_bf16<<<4096,  256, 0, stream>>>(Wq, Wqb, 1048576);
    cvt_bf16<<<4096,  256, 0, stream>>>(Wo, Wob, 1048576);
    prep_k<<<1024, 256, 0, stream>>>(kc, Kwb);
    prep_v<<<256, 256, 0, stream>>>(vc, Vtb);

    gemm_bt<0><<<1024, 256, 0, stream>>>(Xb, Wqb, nullptr, Qb);   // Q + RoPE (pre-scaled)
    attn<<<2048, 512, 0, stream>>>(Qb, Kwb, Vtb, Xb);             // O -> Xb
    gemm_bt<1><<<1024, 256, 0, stream>>>(Xb, Wob, out, nullptr);  // out proj
}

// Round 5
// 444.139 us; speedup vs baseline: 1.2595x; 1.1388x over previous
//
#include <hip/hip_runtime.h>
#include <math.h>

typedef __attribute__((ext_vector_type(8))) short short8;
typedef __attribute__((ext_vector_type(4))) float floatx4;
typedef __attribute__((ext_vector_type(4))) unsigned int uintx4;
typedef __attribute__((ext_vector_type(2))) unsigned int uintx2;

#define MFMA16(a, b, c) __builtin_amdgcn_mfma_f32_16x16x32_bf16((a), (b), (c), 0, 0, 0)

// log2(e) * (1/sqrt(64)) — folded into Q so attention works in exp2 domain
#define QSCALE 0.18033688011112042f

__device__ __forceinline__ unsigned short f2bf(float x) {
    unsigned int u = __float_as_uint(x);
    u += 0x7fffu + ((u >> 16) & 1u);   // round-to-nearest-even
    return (unsigned short)(u >> 16);
}

__device__ __forceinline__ short8 lds8(const unsigned short* p) {
    return *reinterpret_cast<const short8*>(p);
}

// async global->LDS, 16B per lane; LDS dest = wave-uniform base + lane*16
__device__ __forceinline__ void g2l16(const unsigned short* g, unsigned short* l) {
    __builtin_amdgcn_global_load_lds(
        (const __attribute__((address_space(1))) unsigned int*)g,
        (__attribute__((address_space(3))) unsigned int*)l,
        16, 0, 0);
}

// pack two f32 -> bf16x2 dword (RNE): low = a, high = b
__device__ __forceinline__ unsigned int cvtpk(float a, float b) {
    unsigned int r;
    asm("v_cvt_pk_bf16_f32 %0, %1, %2" : "=v"(r) : "v"(a), "v"(b));
    return r;
}

// swap lanes[32:63] of a with lanes[0:31] of b (both modified)
__device__ __forceinline__ void pl32swap(unsigned int& a, unsigned int& b) {
    asm("v_permlane32_swap_b32 %0, %1" : "+v"(a), "+v"(b));
}

// swap odd 16-lane groups of a with even 16-lane groups of b (both modified)
__device__ __forceinline__ void pl16swap(unsigned int& a, unsigned int& b) {
    asm("v_permlane16_swap_b32 %0, %1" : "+v"(a), "+v"(b));
}

// ---------------- prep: fp32 -> bf16 convert (vectorized) ----------------
__global__ void cvt_bf16(const float* __restrict__ src, unsigned short* __restrict__ dst, int n4) {
    int i = blockIdx.x * blockDim.x + threadIdx.x;
    if (i >= n4) return;
    float4 v = reinterpret_cast<const float4*>(src)[i];
    ushort4 o;
    o.x = f2bf(v.x); o.y = f2bf(v.y); o.z = f2bf(v.z); o.w = f2bf(v.w);
    reinterpret_cast<ushort4*>(dst)[i] = o;
}

// ---------------- prep: K window convert (coalesced both sides) ----------------
__global__ void prep_k(const float* __restrict__ kc, unsigned short* __restrict__ Kw) {
    int i = blockIdx.x * blockDim.x + threadIdx.x;   // 0 .. 262143
    int d4  = (i & 15) * 4;
    int s   = (i >> 4) & 1023;
    int bkv = i >> 14;
    size_t src = ((size_t)bkv * 4096 + 3072 + s) * 64 + d4;
    float4 kv = *reinterpret_cast<const float4*>(kc + src);
    ushort4 ko;
    ko.x = f2bf(kv.x); ko.y = f2bf(kv.y); ko.z = f2bf(kv.z); ko.w = f2bf(kv.w);
    *reinterpret_cast<ushort4*>(Kw + ((size_t)bkv * 1024 + s) * 64 + d4) = ko;
}

// ---------------- prep: V window transpose via LDS tile ----------------
__global__ void prep_v(const float* __restrict__ vc, unsigned short* __restrict__ Vt) {
    __shared__ unsigned short tl[64][72];
    const int bkv = blockIdx.x >> 4;
    const int s0  = (blockIdx.x & 15) * 64;
    const int t   = threadIdx.x;
    const int sl  = t >> 2;
    const int dq  = (t & 3) * 16;
    const float* src = vc + ((size_t)bkv * 4096 + 3072 + s0 + sl) * 64 + dq;
    float4 v0 = reinterpret_cast<const float4*>(src)[0];
    float4 v1 = reinterpret_cast<const float4*>(src)[1];
    float4 v2 = reinterpret_cast<const float4*>(src)[2];
    float4 v3 = reinterpret_cast<const float4*>(src)[3];
    tl[dq +  0][sl] = f2bf(v0.x); tl[dq +  1][sl] = f2bf(v0.y);
    tl[dq +  2][sl] = f2bf(v0.z); tl[dq +  3][sl] = f2bf(v0.w);
    tl[dq +  4][sl] = f2bf(v1.x); tl[dq +  5][sl] = f2bf(v1.y);
    tl[dq +  6][sl] = f2bf(v1.z); tl[dq +  7][sl] = f2bf(v1.w);
    tl[dq +  8][sl] = f2bf(v2.x); tl[dq +  9][sl] = f2bf(v2.y);
    tl[dq + 10][sl] = f2bf(v2.z); tl[dq + 11][sl] = f2bf(v2.w);
    tl[dq + 12][sl] = f2bf(v3.x); tl[dq + 13][sl] = f2bf(v3.y);
    tl[dq + 14][sl] = f2bf(v3.z); tl[dq + 15][sl] = f2bf(v3.w);
    __syncthreads();
    const int dl = t >> 2;
    const int sc = (t & 3) * 16;
    unsigned short* dst = Vt + ((size_t)bkv * 64 + dl) * 1024 + s0 + sc;
    short8 x0 = *reinterpret_cast<const short8*>(&tl[dl][sc]);
    short8 x1 = *reinterpret_cast<const short8*>(&tl[dl][sc + 8]);
    *reinterpret_cast<short8*>(dst)     = x0;
    *reinterpret_cast<short8*>(dst + 8) = x1;
}

// ---------------- bf16 MFMA GEMM, 256x256 tile, BK=32, 8 waves ----------------
// T3+T4 pipeline: raw s_barrier + counted vmcnt (stage tile t+2 while
// computing tile t; wait only tile t+1 at iteration end — no vmcnt(0) drain
// in the main loop). LDS is fragment-order (each 16x32 subtile stored in
// exact MFMA lane order) so global_load_lds (linear dest) and ds_read_b128
// (linear read) are both conflict-free by construction. 64 KiB LDS (2 bufs),
// ~195 VGPR, 1 block/CU. EPI=0: RoPE epilogue with f32 cos/sin table built
// into the dead tile LDS after the k-loop (256x32 float2 = exactly 64 KiB).
template <int EPI>
__global__ __launch_bounds__(512, 2)
void gemm256(const unsigned short* __restrict__ A,
             const unsigned short* __restrict__ Bt,
             float* __restrict__ Cf,
             unsigned short* __restrict__ Cb) {
    constexpr int K  = 2048;
    constexpr int NT = 64;                    // K / 32
    __shared__ unsigned short sm[32768];      // 2 bufs x 16384 ush (A:16 + B:16 subtiles x 512)

    const int tid  = threadIdx.x;
    const int lane = tid & 63;
    const int l15  = lane & 15;
    const int quad = lane >> 4;
    const int wid  = tid >> 6;                // 0..7
    const int wr   = wid >> 2;                // 0..1  (M half)
    const int wc   = wid & 3;                 // 0..3  (N quarter)

    const int bn = blockIdx.x & 7;            // XCD-friendly: each XCD owns one bn column
    const int bm = blockIdx.x >> 3;

    // staging sources: wave stages A-subtiles {2w,2w+1} and B-subtiles {2w,2w+1}
    const unsigned short* gA0 = A  + (size_t)(bm * 256 + 2 * wid * 16 + l15) * K + quad * 8;
    const unsigned short* gA1 = gA0 + (size_t)16 * K;
    const unsigned short* gB0 = Bt + (size_t)(bn * 256 + 2 * wid * 16 + l15) * K + quad * 8;
    const unsigned short* gB1 = gB0 + (size_t)16 * K;

    auto STAGE = [&](int t) {
        unsigned short* dst = sm + (t & 1) * 16384 + 2 * wid * 512;
        const int off = t * 32;
        g2l16(gA0 + off, dst);
        g2l16(gA1 + off, dst + 512);
        g2l16(gB0 + off, dst + 8192);
        g2l16(gB1 + off, dst + 8704);
    };

    floatx4 acc[8][4];
#pragma unroll
    for (int i = 0; i < 8; ++i)
#pragma unroll
        for (int j = 0; j < 4; ++j) acc[i][j] = floatx4{0, 0, 0, 0};

    // prologue: stage tiles 0,1; wait tile 0 (tile 1 stays in flight)
    STAGE(0);
    STAGE(1);
    asm volatile("s_waitcnt vmcnt(4)" ::: "memory");
    __builtin_amdgcn_s_barrier();
    asm volatile("" ::: "memory");

    for (int t = 0; t < NT; ++t) {
        const unsigned short* cb = sm + (t & 1) * 16384;

        short8 bf[4], af[8];
#pragma unroll
        for (int j = 0; j < 4; ++j)
            bf[j] = lds8(cb + 8192 + (wc * 4 + j) * 512 + lane * 8);
#pragma unroll
        for (int i = 0; i < 8; ++i)
            af[i] = lds8(cb + (wr * 8 + i) * 512 + lane * 8);

        asm volatile("s_waitcnt lgkmcnt(0)" ::: "memory");
        __builtin_amdgcn_s_barrier();         // all reads of tile t retired
        asm volatile("" ::: "memory");

        if (t + 2 < NT) STAGE(t + 2);         // overwrite dead regions of buf[t&1]

        __builtin_amdgcn_s_setprio(1);
#pragma unroll
        for (int i = 0; i < 8; ++i)
#pragma unroll
            for (int j = 0; j < 4; ++j)
                acc[i][j] = MFMA16(af[i], bf[j], acc[i][j]);
        __builtin_amdgcn_s_setprio(0);

        if (t + 2 < NT) asm volatile("s_waitcnt vmcnt(4)" ::: "memory");  // tile t+1 landed
        else            asm volatile("s_waitcnt vmcnt(0)" ::: "memory");
        __builtin_amdgcn_s_barrier();
        asm volatile("" ::: "memory");
    }

    float2* tabf = reinterpret_cast<float2*>(sm);
    if (EPI == 0) {
        // RoPE table over the dead tile LDS: 256 t x 32 d2 float2 = 64 KiB
        const int t0 = (bm & 15) * 256;
        for (int e = tid; e < 8192; e += 512) {
            int tl = e >> 5, d2 = e & 31;
            float f = (float)(t0 + tl) * exp2f(-(float)d2 * 0.41524101186092f);
            float sn, cs; __sincosf(f, &sn, &cs);
            tabf[tl * 32 + d2] = make_float2(cs, sn);
        }
        __syncthreads();
    }

#pragma unroll
    for (int i = 0; i < 8; ++i)
#pragma unroll
        for (int j = 0; j < 4; ++j)
#pragma unroll
            for (int r = 0; r < 4; ++r) {
                int row = bm * 256 + wr * 128 + i * 16 + quad * 4 + r;
                int col = bn * 256 + wc * 64 + j * 16 + l15;
                float v = acc[i][j][r];
                if (EPI == 0) {
                    float p = __shfl_xor(v, 1);
                    int t_ = row & 4095, b_ = row >> 12;
                    int hh = col >> 6, d = col & 63;
                    int tl = wr * 128 + i * 16 + quad * 4 + r;
                    float2 cspair = tabf[tl * 32 + (d >> 1)];
                    float o = (d & 1) ? (p * cspair.y + v * cspair.x)
                                      : (v * cspair.x - p * cspair.y);
                    o *= QSCALE;
                    float po = __shfl_xor(o, 1);
                    if (!(lane & 1)) {
                        unsigned int pk = (unsigned int)f2bf(o) |
                                          ((unsigned int)f2bf(po) << 16);
                        *reinterpret_cast<unsigned int*>(
                            Cb + ((size_t)((b_ * 32 + hh) * 4096 + t_)) * 64 + d) = pk;
                    }
                } else {
                    Cf[(size_t)row * 2048 + col] = v;
                }
            }
}

// ---------------- flash attention over 1024-key window ----------------
// Swapped-operand form (T12) + in-register P repack; 512-thread / 8-wave
// blocks covering 128 queries; K/V LDS tiles shared by 8 waves.
__global__ __launch_bounds__(512, 8)
void attn(const unsigned short* __restrict__ Q,
          const unsigned short* __restrict__ Kw,
          const unsigned short* __restrict__ Vt,
          unsigned short* __restrict__ O) {
    const int blk  = blockIdx.x;
    const int qblk = blk & 31;          // 32 blocks of 128 queries
    const int bh   = blk >> 5;
    const int h    = bh & 31;
    const int b    = bh >> 5;
    const int kvh  = h >> 2;

    const int tid  = threadIdx.x;
    const int lane = tid & 63;
    const int l15  = lane & 15;
    const int quad = lane >> 4;
    const int wid  = tid >> 6;          // 0..7
    const int qt0  = qblk * 128 + wid * 16;

    const unsigned short* Qp = Q  + ((size_t)bh * 4096 + qt0) * 64;
    const unsigned short* Kp = Kw + (size_t)(b * 8 + kvh) * 1024 * 64;
    const unsigned short* Vp = Vt + (size_t)(b * 8 + kvh) * 64 * 1024;

    // [buf][frag(8) * 512 + lane*8]; frag (c*2+half) for K, (j*2+shalf) for V
    __shared__ unsigned short Ks[2][4096];
    __shared__ unsigned short Vs[2][4096];

    short8 qa0 = lds8(&Qp[l15 * 64 + quad * 8]);
    short8 qa1 = lds8(&Qp[l15 * 64 + 32 + quad * 8]);

    // staging: wave w stages K frag f=w (chunk c=w>>1, k-half w&1) and
    // V frag f=w (d-group j=w>>1, key-half w&1)
    const unsigned short* gK = Kp + (size_t)((wid >> 1) * 16 + l15) * 64
                                  + (wid & 1) * 32 + quad * 8;
    const unsigned short* gV = Vp + (size_t)((wid >> 1) * 16 + l15) * 1024
                                  + (wid & 1) * 32 + quad * 8;
    unsigned short* sK0 = &Ks[0][wid * 512];
    unsigned short* sK1 = &Ks[1][wid * 512];
    unsigned short* sV0 = &Vs[0][wid * 512];
    unsigned short* sV1 = &Vs[1][wid * 512];

    const int ntiles = (qblk < 7 ? 2 * qblk + 2 : 16);      // block-uniform
    const int nkW    = (qt0 + 16 < 1024) ? qt0 + 16 : 1024; // per-wave keys
    const int ntW    = (nkW + 63) >> 6;                     // wave's tile count
    const bool diagW = (qt0 < 1024);

    // prefetch tile 0
    g2l16(gK, sK0);
    g2l16(gV, sV0);

    floatx4 o0 = {0,0,0,0}, o1 = {0,0,0,0}, o2 = {0,0,0,0}, o3 = {0,0,0,0};
    float Lq = 0.f;
    float m = -INFINITY;

    for (int it = 0; it < ntiles; ++it) {
        __syncthreads();                         // staging of tile `it` complete
        const int cur = it & 1;
        if (it + 1 < ntiles) {                   // prefetch next into other buffer
            g2l16(gK + (it + 1) * 4096, cur ? sK0 : sK1);
            g2l16(gV + (it + 1) * 64,   cur ? sV0 : sV1);
        }
        if (it >= ntW) continue;                 // wave done (barriers stay uniform)
        const int s0 = it << 6;
        const unsigned short* Kc = Ks[cur];
        const unsigned short* Vc = Vs[cur];

        // S^T = K·Q^T: lane holds S[key = s0 + c*16 + quad*4 + r][query = qt0 + l15]
        floatx4 sS[4];
#pragma unroll
        for (int c = 0; c < 4; ++c) {
            floatx4 z = {0, 0, 0, 0};
            z = MFMA16(lds8(Kc + c * 1024 + lane * 8), qa0, z);
            z = MFMA16(lds8(Kc + c * 1024 + 512 + lane * 8), qa1, z);
            sS[c] = z;
        }

        const bool last = (it == ntW - 1);
        bool skipHi = false;
        if (last && diagW) {                     // diagonal tile: causal mask
#pragma unroll
            for (int c = 0; c < 4; ++c)
#pragma unroll
                for (int r = 0; r < 4; ++r)
                    if (s0 + c * 16 + quad * 4 + r > qt0 + l15) sS[c][r] = -INFINITY;
            skipHi = (nkW - s0 <= 32);
        }

        // per-query tile max: max3 tree + quad reduce (keys live on quad bits)
        float t0 = fmaxf(fmaxf(sS[0][0], sS[0][1]), fmaxf(sS[0][2], sS[0][3]));
        float t1 = fmaxf(fmaxf(sS[1][0], sS[1][1]), fmaxf(sS[1][2], sS[1][3]));
        float t2 = fmaxf(fmaxf(sS[2][0], sS[2][1]), fmaxf(sS[2][2], sS[2][3]));
        float t3 = fmaxf(fmaxf(sS[3][0], sS[3][1]), fmaxf(sS[3][2], sS[3][3]));
        float mx = fmaxf(fmaxf(t0, t1), fmaxf(t2, t3));
        mx = fmaxf(mx, __shfl_xor(mx, 16));
        mx = fmaxf(mx, __shfl_xor(mx, 32));      // quad-uniform per query l15

        // defer-max (T13): only rescale when tile max exceeds m by > 8
        if (!__all(mx <= m + 8.0f)) {
            const float mn = fmaxf(m, mx);       // quad-uniform per query
            const float alpha = exp2f(m - mn);   // m=-inf first tile -> alpha=0
            m = mn;
            o0 *= alpha; o1 *= alpha; o2 *= alpha; o3 *= alpha;
            Lq *= alpha;
        }

        float p[4][4];
#pragma unroll
        for (int c = 0; c < 4; ++c)
#pragma unroll
            for (int r = 0; r < 4; ++r) p[c][r] = exp2f(sS[c][r] - m);
        Lq += ((p[0][0] + p[0][1] + p[0][2] + p[0][3]) + (p[1][0] + p[1][1] + p[1][2] + p[1][3]))
            + ((p[2][0] + p[2][1] + p[2][2] + p[2][3]) + (p[3][0] + p[3][1] + p[3][2] + p[3][3]));

        // in-register P repack: keys 0-31 (chunks 0,1) -> pa_lo
        unsigned int a0 = cvtpk(p[0][0], p[0][1]);
        unsigned int a1 = cvtpk(p[0][2], p[0][3]);
        unsigned int a2 = cvtpk(p[1][0], p[1][1]);
        unsigned int a3 = cvtpk(p[1][2], p[1][3]);
        pl32swap(a0, a2); pl32swap(a1, a3);
        pl16swap(a0, a2); pl16swap(a1, a3);
        uintx4 tlo = {a0, a1, a2, a3};
        short8 pa_lo = __builtin_bit_cast(short8, tlo);

        // O^T += V^T · P^T : A-frag = V^T (same LDS frags), B-frag = pa
        o0 = MFMA16(lds8(Vc + 0 * 512 + lane * 8), pa_lo, o0);
        o1 = MFMA16(lds8(Vc + 2 * 512 + lane * 8), pa_lo, o1);
        o2 = MFMA16(lds8(Vc + 4 * 512 + lane * 8), pa_lo, o2);
        o3 = MFMA16(lds8(Vc + 6 * 512 + lane * 8), pa_lo, o3);
        if (!skipHi) {
            // keys 32-63 (chunks 2,3) -> pa_hi
            unsigned int b0 = cvtpk(p[2][0], p[2][1]);
            unsigned int b1 = cvtpk(p[2][2], p[2][3]);
            unsigned int b2 = cvtpk(p[3][0], p[3][1]);
            unsigned int b3 = cvtpk(p[3][2], p[3][3]);
            pl32swap(b0, b2); pl32swap(b1, b3);
            pl16swap(b0, b2); pl16swap(b1, b3);
            uintx4 thi = {b0, b1, b2, b3};
            short8 pa_hi = __builtin_bit_cast(short8, thi);
            o0 = MFMA16(lds8(Vc + 1 * 512 + lane * 8), pa_hi, o0);
            o1 = MFMA16(lds8(Vc + 3 * 512 + lane * 8), pa_hi, o1);
            o2 = MFMA16(lds8(Vc + 5 * 512 + lane * 8), pa_hi, o2);
            o3 = MFMA16(lds8(Vc + 7 * 512 + lane * 8), pa_hi, o3);
        }
    }

    // Lq holds this lane's keys only; total = sum across quads
    Lq += __shfl_xor(Lq, 16);
    Lq += __shfl_xor(Lq, 32);
    const float inv = 1.f / Lq;

    // O^T layout: lane holds O[q = qt0+l15][d = j*16 + quad*4 + r] -> 8B stores
    unsigned short* Op = O + (size_t)b * 4096 * 2048 + (size_t)(qt0 + l15) * 2048
                           + h * 64 + quad * 4;
    uintx2 w0, w1, w2, w3;
    w0.x = cvtpk(o0[0] * inv, o0[1] * inv); w0.y = cvtpk(o0[2] * inv, o0[3] * inv);
    w1.x = cvtpk(o1[0] * inv, o1[1] * inv); w1.y = cvtpk(o1[2] * inv, o1[3] * inv);
    w2.x = cvtpk(o2[0] * inv, o2[1] * inv); w2.y = cvtpk(o2[2] * inv, o2[3] * inv);
    w3.x = cvtpk(o3[0] * inv, o3[1] * inv); w3.y = cvtpk(o3[2] * inv, o3[3] * inv);
    *reinterpret_cast<uintx2*>(Op)      = w0;
    *reinterpret_cast<uintx2*>(Op + 16) = w1;
    *reinterpret_cast<uintx2*>(Op + 32) = w2;
    *reinterpret_cast<uintx2*>(Op + 48) = w3;
}

// ---------------- launch ----------------
extern "C" void kernel_launch(void* const* d_in, const int* in_sizes, int n_in,
                              void* d_out, int out_size, void* d_ws, size_t ws_size,
                              hipStream_t stream) {
    const float* x  = (const float*)d_in[0];
    const float* kc = (const float*)d_in[1];
    const float* vc = (const float*)d_in[2];
    const float* Wq = (const float*)d_in[3];
    const float* Wo = (const float*)d_in[4];
    float* out = (float*)d_out;

    char* ws = (char*)d_ws;
    unsigned short* Xb  = (unsigned short*)(ws);              // 33,554,432 B (reused as O)
    unsigned short* Qb  = (unsigned short*)(ws + 33554432);   // 33,554,432 B
    unsigned short* Wqb = (unsigned short*)(ws + 67108864);   //  8,388,608 B
    unsigned short* Wob = (unsigned short*)(ws + 75497472);   //  8,388,608 B
    unsigned short* Kwb = (unsigned short*)(ws + 83886080);   //  2,097,152 B
    unsigned short* Vtb = (unsigned short*)(ws + 85983232);   //  2,097,152 B

    cvt_bf16<<<16384, 256, 0, stream>>>(x,  Xb,  4194304);
    cvt_bf16<<<4096,  256, 0, stream>>>(Wq, Wqb, 1048576);
    cvt_bf16<<<4096,  256, 0, stream>>>(Wo, Wob, 1048576);
    prep_k<<<1024, 256, 0, stream>>>(kc, Kwb);
    prep_v<<<256, 256, 0, stream>>>(vc, Vtb);

    gemm256<0><<<256, 512, 0, stream>>>(Xb, Wqb, nullptr, Qb);   // Q + RoPE (pre-scaled)
    attn<<<2048, 512, 0, stream>>>(Qb, Kwb, Vtb, Xb);            // O -> Xb
    gemm256<1><<<256, 512, 0, stream>>>(Xb, Wob, out, nullptr);  // out proj
}